// Round 17
// baseline (277.537 us; speedup 1.0000x reference)
//
#include <hip/hip_runtime.h>
#include <math.h>

#define BB 512
#define NN 1000
#define DD 128
#define HH 8
#define TILE 64    // 16 tiles (last has 40 rows); 64*32 = 2048 float4/tile
#define NT 16

// ws layout: flag@0 (4B) | Afold@4096: [B][128][8] f32 (2 MB)
#define WS_AFOLD 4096

__device__ __forceinline__ bool mask_feasible(const void* mask, int flag, int idx) {
    if (flag == 1) return ((const int*)mask)[idx] != 0;
    if (flag == 2) return ((const float*)mask)[idx] != 0.0f;
    return ((const unsigned char*)mask)[idx] != 0;
}

__device__ __forceinline__ float rdl(float v, int srclane) {
    return __int_as_float(__builtin_amdgcn_readlane(__float_as_int(v), srclane));
}

// async 16B global->LDS (no VGPR round-trip). lds dest must be wave-uniform
// base (+ lane*16 done by HW); global src is per-lane.
__device__ __forceinline__ void gload_lds16(const float4* g, float4* l) {
    __builtin_amdgcn_global_load_lds(
        (const __attribute__((address_space(1))) void*)g,
        (__attribute__((address_space(3))) void*)l,
        16, 0, 0);
}

// Detect action_mask storage dtype from its first 64 32-bit words.
__global__ void k0_detect(const unsigned int* __restrict__ m, int* __restrict__ flag) {
    int t = threadIdx.x;
    unsigned int w = m[t];
    unsigned long long bi = __ballot(w <= 1u);
    unsigned long long bf = __ballot(w == 0u || w == 0x3F800000u);
    if (t == 0) {
        int f = 0;
        if (bi == ~0ull) f = 1;
        else if (bf == ~0ull) f = 2;
        *flag = f;
    }
}

// Fused: mean over N -> q = mean@W_fixed + ctx@W_step -> Afold[c][h]
// (validated R4/R12; single-arg launch_bounds only — R5: 2nd arg caused spill.)
__global__ __launch_bounds__(512) void kA_meanfold(
    const float* __restrict__ emb, const float* __restrict__ ctx,
    const float* __restrict__ W_fixed, const float* __restrict__ W_step,
    const float* __restrict__ W_node, float* __restrict__ Afold) {
    int b = blockIdx.x, t = threadIdx.x;
    __shared__ float4 red[512];
    __shared__ float mean_s[DD], cld[2 * DD], qlds[DD];
    int q4 = t & 31, j = t >> 5;
    const float4* e4 = (const float4*)(emb + (size_t)b * NN * DD);
    float4 acc = {0.f, 0.f, 0.f, 0.f};
    for (int n = j; n < NN; n += 16) {
        float4 v = e4[n * 32 + q4];
        acc.x += v.x; acc.y += v.y; acc.z += v.z; acc.w += v.w;
    }
    red[t] = acc;
    __syncthreads();
    for (int s = 8; s >= 1; s >>= 1) {
        if (j < s) {
            float4 o = red[t + s * 32], m = red[t];
            m.x += o.x; m.y += o.y; m.z += o.z; m.w += o.w;
            red[t] = m;
        }
        __syncthreads();
    }
    if (t < 32) {
        float4 m = red[t];
        const float inv = 1.0f / (float)NN;
        ((float4*)mean_s)[t] = make_float4(m.x * inv, m.y * inv, m.z * inv, m.w * inv);
    }
    if (t < 256) cld[t] = ctx[b * 2 * DD + t];
    __syncthreads();
    if (t < 128) {
        float a = 0.f;
        for (int c = 0; c < DD; ++c)     a += mean_s[c] * W_fixed[c * DD + t];
        for (int c = 0; c < 2 * DD; ++c) a += cld[c] * W_step[c * DD + t];
        qlds[t] = a;
    }
    __syncthreads();
    if (t < 128) {
        const float* wrow = W_node + (size_t)t * 3 * DD;   // Wk cols [0,128)
        float* A2 = Afold + (size_t)b * 1024;
        for (int h = 0; h < HH; ++h) {
            float a = 0.f;
#pragma unroll
            for (int d0 = 0; d0 < 16; ++d0) a += wrow[h * 16 + d0] * qlds[h * 16 + d0];
            A2[t * 8 + h] = 0.25f * a;   // 1/sqrt(dk) folded
        }
    }
}

// R12 flash with async double-buffered staging via global_load_lds.
// TILE=64, two 32KB LDS buffers; LDS dest linear, global source pre-swizzled
// so the effective layout (phys col = logical col ^ (row&31)) matches R12.
// Wave w computes heads {2w, 2w+1} for row n = lane. 2 barriers/tile.
__global__ __launch_bounds__(256) void kB_flash(
    const float* __restrict__ emb, const float* __restrict__ Afold,
    const void* __restrict__ mask, const int* __restrict__ flagp,
    const float* __restrict__ W_node, const float* __restrict__ W_out,
    float* __restrict__ out) {
    int b = blockIdx.x, t = threadIdx.x;
    int flag = *flagp;
    int wave = t >> 6, lane = t & 63;
    int c4 = t & 31, jr = t >> 5;        // accumulate role (jr 0..7)
    int h0 = wave * 2;                   // this wave's head pair

    __shared__ float4 buf[2][TILE * 32]; // 2 x 32 KB staged tiles (phys-swizzled)
    __shared__ float cbuf[HH][72];       // p values, padded rows (bank-spread)
    __shared__ float wemb_s[8][128];
    __shared__ float small[3 * DD];      // hl / gl / g2
    __shared__ float zl[HH];

    // A lane-distributed: lane l holds A[l][h0..h0+1], A[64+l][h0..h0+1]
    const float* Ab = Afold + (size_t)b * 1024;
    float a0l = Ab[lane * 8 + h0],        a1l = Ab[lane * 8 + h0 + 1];
    float a0h = Ab[(64 + lane) * 8 + h0], a1h = Ab[(64 + lane) * 8 + h0 + 1];

    float4 wacc[8];
#pragma unroll
    for (int h = 0; h < HH; ++h) wacc[h] = make_float4(0.f, 0.f, 0.f, 0.f);
    float zrun = 0.f;                    // meaningful on t<8 only

    const float4* embB4 = (const float4*)(emb + (size_t)b * NN * DD);
    const int mbase = b * NN;

    // ---- stage one tile asynchronously: 8 wave-uniform issues per wave ----
    auto stage = [&](int dst, int n0, int rows) {
#pragma unroll
        for (int idx = 0; idx < 8; ++idx) {
            int p0 = idx * 256 + wave * 64;          // wave-uniform LDS base
            if (p0 < rows * 32) {
                int p = p0 + lane;                   // this lane's linear pos
                int r = p >> 5;
                int c = (p & 31) ^ (r & 31);         // pre-swizzled source col
                gload_lds16(embB4 + (size_t)(n0 + r) * 32 + c, &buf[dst][p0]);
            }
        }
    };

    // prologue: tile 0
    stage(0, 0, TILE);
    __syncthreads();                                  // drains vmcnt

    for (int tile = 0; tile < NT; ++tile) {
        int n0 = tile * TILE;
        int rows = (NN - n0 < TILE) ? (NN - n0) : TILE;
        int cur = tile & 1;
        // issue next tile's async loads (overlap with compat below)
        if (tile < NT - 1) {
            int n1 = n0 + TILE;
            int rows1 = (NN - n1 < TILE) ? (NN - n1) : TILE;
            stage(cur ^ 1, n1, rows1);
        }
        const float4* tb = buf[cur];
        // ---- compat: row = lane, heads {h0, h0+1}; 4 independent FMA chains ----
        if (lane < rows) {
            int sw = lane & 31;
            float s0a = 0.f, s0b = 0.f, s1a = 0.f, s1b = 0.f;
#pragma unroll
            for (int k = 0; k < 16; ++k) {
                float4 eL = tb[lane * 32 + (k ^ sw)];          // cols 4k..4k+3
                float4 eH = tb[lane * 32 + ((k + 16) ^ sw)];   // cols 64+4k..
                int c = k * 4;
                s0a += eL.x * rdl(a0l, c) + eL.y * rdl(a0l, c + 1) + eL.z * rdl(a0l, c + 2) + eL.w * rdl(a0l, c + 3);
                s1a += eL.x * rdl(a1l, c) + eL.y * rdl(a1l, c + 1) + eL.z * rdl(a1l, c + 2) + eL.w * rdl(a1l, c + 3);
                s0b += eH.x * rdl(a0h, c) + eH.y * rdl(a0h, c + 1) + eH.z * rdl(a0h, c + 2) + eH.w * rdl(a0h, c + 3);
                s1b += eH.x * rdl(a1h, c) + eH.y * rdl(a1h, c + 1) + eH.z * rdl(a1h, c + 2) + eH.w * rdl(a1h, c + 3);
            }
            bool feas = mask_feasible(mask, flag, mbase + n0 + lane);
            cbuf[h0][lane]     = feas ? __expf(s0a + s0b) : 0.f;
            cbuf[h0 + 1][lane] = feas ? __expf(s1a + s1b) : 0.f;
        }
        __syncthreads();
        // ---- z mini-reduce (wave 0; other waves proceed to accumulate) ----
        if (t < 64) {
            int h = t & 7, seg = t >> 3;
            float z = 0.f;
            for (int nn = seg; nn < rows; nn += 8) z += cbuf[h][nn];
            z += __shfl_xor(z, 8);
            z += __shfl_xor(z, 16);
            z += __shfl_xor(z, 32);
            if (t < 8) zrun += z;
        }
        // ---- accumulate wemb from LDS tile (p broadcast from cbuf) ----
        for (int nn = jr; nn < rows; nn += 8) {
            float4 e = tb[nn * 32 + (c4 ^ (nn & 31))];
            float p0 = cbuf[0][nn], p1 = cbuf[1][nn], p2 = cbuf[2][nn], p3 = cbuf[3][nn];
            float p4 = cbuf[4][nn], p5 = cbuf[5][nn], p6 = cbuf[6][nn], p7 = cbuf[7][nn];
            wacc[0].x += p0 * e.x; wacc[0].y += p0 * e.y; wacc[0].z += p0 * e.z; wacc[0].w += p0 * e.w;
            wacc[1].x += p1 * e.x; wacc[1].y += p1 * e.y; wacc[1].z += p1 * e.z; wacc[1].w += p1 * e.w;
            wacc[2].x += p2 * e.x; wacc[2].y += p2 * e.y; wacc[2].z += p2 * e.z; wacc[2].w += p2 * e.w;
            wacc[3].x += p3 * e.x; wacc[3].y += p3 * e.y; wacc[3].z += p3 * e.z; wacc[3].w += p3 * e.w;
            wacc[4].x += p4 * e.x; wacc[4].y += p4 * e.y; wacc[4].z += p4 * e.z; wacc[4].w += p4 * e.w;
            wacc[5].x += p5 * e.x; wacc[5].y += p5 * e.y; wacc[5].z += p5 * e.z; wacc[5].w += p5 * e.w;
            wacc[6].x += p6 * e.x; wacc[6].y += p6 * e.y; wacc[6].z += p6 * e.z; wacc[6].w += p6 * e.w;
            wacc[7].x += p7 * e.x; wacc[7].y += p7 * e.y; wacc[7].z += p7 * e.z; wacc[7].w += p7 * e.w;
        }
        __syncthreads();   // cbuf + buf[cur] dead; next tile's buffer complete
    }
    if (t < 8) zl[t] = zrun;
    // ---- j-reduce wemb partials (buf reused as [8][32][8] f4 scratch), normalize ----
    {
        float4* red = (float4*)buf;
#pragma unroll
        for (int h = 0; h < HH; ++h) red[(jr * 32 + c4) * 8 + h] = wacc[h];
        __syncthreads();
        int cc = t >> 3, hh = t & 7;
        float4 s = make_float4(0.f, 0.f, 0.f, 0.f);
#pragma unroll
        for (int jj = 0; jj < 8; ++jj) {
            float4 v = red[(jj * 32 + cc) * 8 + hh];
            s.x += v.x; s.y += v.y; s.z += v.z; s.w += v.w;
        }
        float inv = 1.0f / zl[hh];
        s.x *= inv; s.y *= inv; s.z *= inv; s.w *= inv;
        *(float4*)&wemb_s[hh][cc * 4] = s;
    }
    __syncthreads();
    // ---- glimpse tail ----
    if (t < 128) {
        int h = t >> 4;
        float a = 0.f;
        for (int c = 0; c < DD; ++c) a += wemb_s[h][c] * W_node[(size_t)c * 384 + 128 + t];
        small[t] = a;                          // hl
    }
    __syncthreads();
    if (t < 128) {
        float g = 0.f;
        for (int k = 0; k < DD; ++k) g += small[k] * W_out[k * DD + t];
        small[128 + t] = g;                    // gl
    }
    __syncthreads();
    if (t < 128) {
        float a3 = 0.f;
        const float* wr = W_node + (size_t)t * 384 + 256;   // Wl row t
        for (int d = 0; d < DD; ++d) a3 += wr[d] * small[128 + d];
        small[256 + t] = a3;                   // g2
    }
    __syncthreads();
    // ---- logits tail ----
    const float4* g2v = (const float4*)&small[256];
    for (int r = t; r < NN; r += 256) {
        const float4* row = embB4 + (size_t)r * 32;
        float acc = 0.f;
#pragma unroll 8
        for (int k = 0; k < 32; ++k) {
            float4 e = row[k], g = g2v[k];
            acc += e.x * g.x + e.y * g.y + e.z * g.z + e.w * g.w;
        }
        bool feas = mask_feasible(mask, flag, mbase + r);
        out[(size_t)mbase + r] = feas ? (10.0f * tanhf(acc * 0.08838834764831845f)) : -1.0e30f;
    }
}

extern "C" void kernel_launch(void* const* d_in, const int* in_sizes, int n_in,
                              void* d_out, int out_size, void* d_ws, size_t ws_size,
                              hipStream_t stream) {
    (void)in_sizes; (void)n_in; (void)out_size; (void)ws_size;
    const float* emb     = (const float*)d_in[0];
    const float* ctx     = (const float*)d_in[1];
    const float* W_node  = (const float*)d_in[2];
    const float* W_fixed = (const float*)d_in[3];
    const float* W_step  = (const float*)d_in[4];
    const float* W_out   = (const float*)d_in[5];
    const void*  mask    = d_in[6];
    float* out = (float*)d_out;

    char* ws = (char*)d_ws;
    int*   flag  = (int*)(ws + 0);
    float* Afold = (float*)(ws + WS_AFOLD);

    k0_detect<<<1, 64, 0, stream>>>((const unsigned int*)mask, flag);
    kA_meanfold<<<BB, 512, 0, stream>>>(emb, ctx, W_fixed, W_step, W_node, Afold);
    kB_flash<<<BB, 256, 0, stream>>>(emb, Afold, mask, flag, W_node, W_out, out);
}

// Round 18
// 184.898 us; speedup vs baseline: 1.5010x; 1.5010x over previous
//
#include <hip/hip_runtime.h>
#include <math.h>

#define BB 512
#define NN 1000
#define DD 128
#define HH 8
#define TILE 125   // 8 tiles of 125 rows; 4000 float4/tile

// ws layout: flag@0 (4B) | Afold@4096: [B][128][8] f32 (2 MB)
#define WS_AFOLD 4096

__device__ __forceinline__ bool mask_feasible(const void* mask, int flag, int idx) {
    if (flag == 1) return ((const int*)mask)[idx] != 0;
    if (flag == 2) return ((const float*)mask)[idx] != 0.0f;
    return ((const unsigned char*)mask)[idx] != 0;
}

__device__ __forceinline__ float rdl(float v, int srclane) {
    return __int_as_float(__builtin_amdgcn_readlane(__float_as_int(v), srclane));
}

// async 16B global->LDS DMA: per-lane global src addr; LDS dest is
// wave-uniform base + lane*16 (HW). No VGPR round-trip, can't spill.
__device__ __forceinline__ void gload_lds16(const float4* g, float4* l) {
    __builtin_amdgcn_global_load_lds(
        (const __attribute__((address_space(1))) void*)g,
        (__attribute__((address_space(3))) void*)l,
        16, 0, 0);
}

// Detect action_mask storage dtype from its first 64 32-bit words.
__global__ void k0_detect(const unsigned int* __restrict__ m, int* __restrict__ flag) {
    int t = threadIdx.x;
    unsigned int w = m[t];
    unsigned long long bi = __ballot(w <= 1u);
    unsigned long long bf = __ballot(w == 0u || w == 0x3F800000u);
    if (t == 0) {
        int f = 0;
        if (bi == ~0ull) f = 1;
        else if (bf == ~0ull) f = 2;
        *flag = f;
    }
}

// Fused: mean over N -> q = mean@W_fixed + ctx@W_step -> Afold[c][h]
// (validated R4/R12; single-arg launch_bounds only — R5: 2nd arg caused spill.)
__global__ __launch_bounds__(512) void kA_meanfold(
    const float* __restrict__ emb, const float* __restrict__ ctx,
    const float* __restrict__ W_fixed, const float* __restrict__ W_step,
    const float* __restrict__ W_node, float* __restrict__ Afold) {
    int b = blockIdx.x, t = threadIdx.x;
    __shared__ float4 red[512];
    __shared__ float mean_s[DD], cld[2 * DD], qlds[DD];
    int q4 = t & 31, j = t >> 5;
    const float4* e4 = (const float4*)(emb + (size_t)b * NN * DD);
    float4 acc = {0.f, 0.f, 0.f, 0.f};
    for (int n = j; n < NN; n += 16) {
        float4 v = e4[n * 32 + q4];
        acc.x += v.x; acc.y += v.y; acc.z += v.z; acc.w += v.w;
    }
    red[t] = acc;
    __syncthreads();
    for (int s = 8; s >= 1; s >>= 1) {
        if (j < s) {
            float4 o = red[t + s * 32], m = red[t];
            m.x += o.x; m.y += o.y; m.z += o.z; m.w += o.w;
            red[t] = m;
        }
        __syncthreads();
    }
    if (t < 32) {
        float4 m = red[t];
        const float inv = 1.0f / (float)NN;
        ((float4*)mean_s)[t] = make_float4(m.x * inv, m.y * inv, m.z * inv, m.w * inv);
    }
    if (t < 256) cld[t] = ctx[b * 2 * DD + t];
    __syncthreads();
    if (t < 128) {
        float a = 0.f;
        for (int c = 0; c < DD; ++c)     a += mean_s[c] * W_fixed[c * DD + t];
        for (int c = 0; c < 2 * DD; ++c) a += cld[c] * W_step[c * DD + t];
        qlds[t] = a;
    }
    __syncthreads();
    if (t < 128) {
        const float* wrow = W_node + (size_t)t * 3 * DD;   // Wk cols [0,128)
        float* A2 = Afold + (size_t)b * 1024;
        for (int h = 0; h < HH; ++h) {
            float a = 0.f;
#pragma unroll
            for (int d0 = 0; d0 < 16; ++d0) a += wrow[h * 16 + d0] * qlds[h * 16 + d0];
            A2[t * 8 + h] = 0.25f * a;   // 1/sqrt(dk) folded
        }
    }
}

// R12's measured-best kB with ONE delta: staging via global_load_lds DMA
// (63 wave-uniform issues/block vs ~32 insts/thread/tile). LDS layout is
// byte-identical to R12 (source address pre-swizzled); read side untouched.
__global__ __launch_bounds__(256) void kB_flash(
    const float* __restrict__ emb, const float* __restrict__ Afold,
    const void* __restrict__ mask, const int* __restrict__ flagp,
    const float* __restrict__ W_node, const float* __restrict__ W_out,
    float* __restrict__ out) {
    int b = blockIdx.x, t = threadIdx.x;
    int flag = *flagp;
    int wave = t >> 6, lane = t & 63;
    int hq = (t >> 7) * 4;               // waves 0,1 -> h0..3 ; 2,3 -> h4..7
    int n = t & 127;                     // compat row (valid < TILE)
    int c4 = t & 31, jr = t >> 5;        // accumulate role (jr 0..7)

    __shared__ float4 tile4[128][32];    // 64 KB staged tile (XOR-swizzled); reused as j-reduce scratch
    __shared__ float cbuf[128][8];       // 4 KB: p values
    __shared__ float wemb_s[8][128];
    __shared__ float small[3 * DD];      // hl / gl / g2
    __shared__ float zl[HH];

    // A lane-distributed: lane l holds A[l][hq+h'], A[64+l][hq+h']
    const float* Ab = Afold + (size_t)b * 1024;
    float a0l = Ab[lane * 8 + hq + 0], a1l = Ab[lane * 8 + hq + 1];
    float a2l = Ab[lane * 8 + hq + 2], a3l = Ab[lane * 8 + hq + 3];
    float a0h = Ab[(64 + lane) * 8 + hq + 0], a1h = Ab[(64 + lane) * 8 + hq + 1];
    float a2h = Ab[(64 + lane) * 8 + hq + 2], a3h = Ab[(64 + lane) * 8 + hq + 3];

    float4 wacc[8];
#pragma unroll
    for (int h = 0; h < HH; ++h) wacc[h] = make_float4(0.f, 0.f, 0.f, 0.f);
    float zrun = 0.f;                    // meaningful on t<8 only

    const float4* embB4 = (const float4*)(emb + (size_t)b * NN * DD);
    const int mbase = b * NN;
    float4* tl = (float4*)tile4;

    for (int tile = 0; tile < 8; ++tile) {
        int n0 = tile * TILE;
        // ---- stage tile -> LDS via async DMA (wave-uniform LDS base,
        //      per-lane pre-swizzled global source; layout == R12) ----
        for (int i = wave; i < 63; i += 4) {
            int p0 = i * 64;                     // wave-uniform linear base
            int p = p0 + lane;
            int r = p >> 5; if (r > 124) r = 124;   // clamp tail overread
            int c = (p & 31) ^ (r & 31);
            gload_lds16(embB4 + (size_t)(n0 + r) * 32 + c, &tl[p0]);
        }
        __syncthreads();                         // drains vmcnt before reads
        // ---- compat from LDS -> p = exp(compat) (no max-sub; validated R12) ----
        if (n < TILE) {
            int sw = n & 31;
            float4 s = make_float4(0.f, 0.f, 0.f, 0.f);
#pragma unroll 4
            for (int k = 0; k < 16; ++k) {          // cols 0..63
                float4 e = tile4[n][k ^ sw];
                int c = k * 4;
                s.x += e.x * rdl(a0l, c) + e.y * rdl(a0l, c + 1) + e.z * rdl(a0l, c + 2) + e.w * rdl(a0l, c + 3);
                s.y += e.x * rdl(a1l, c) + e.y * rdl(a1l, c + 1) + e.z * rdl(a1l, c + 2) + e.w * rdl(a1l, c + 3);
                s.z += e.x * rdl(a2l, c) + e.y * rdl(a2l, c + 1) + e.z * rdl(a2l, c + 2) + e.w * rdl(a2l, c + 3);
                s.w += e.x * rdl(a3l, c) + e.y * rdl(a3l, c + 1) + e.z * rdl(a3l, c + 2) + e.w * rdl(a3l, c + 3);
            }
#pragma unroll 4
            for (int k = 16; k < 32; ++k) {         // cols 64..127
                float4 e = tile4[n][k ^ sw];
                int c = k * 4 - 64;
                s.x += e.x * rdl(a0h, c) + e.y * rdl(a0h, c + 1) + e.z * rdl(a0h, c + 2) + e.w * rdl(a0h, c + 3);
                s.y += e.x * rdl(a1h, c) + e.y * rdl(a1h, c + 1) + e.z * rdl(a1h, c + 2) + e.w * rdl(a1h, c + 3);
                s.z += e.x * rdl(a2h, c) + e.y * rdl(a2h, c + 1) + e.z * rdl(a2h, c + 2) + e.w * rdl(a2h, c + 3);
                s.w += e.x * rdl(a3h, c) + e.y * rdl(a3h, c + 1) + e.z * rdl(a3h, c + 2) + e.w * rdl(a3h, c + 3);
            }
            bool feas = mask_feasible(mask, flag, mbase + n0 + n);
            float4 p = make_float4(0.f, 0.f, 0.f, 0.f);
            if (feas) {
                p.x = __expf(s.x); p.y = __expf(s.y);
                p.z = __expf(s.z); p.w = __expf(s.w);
            }
            *(float4*)&cbuf[n][hq] = p;
        }
        __syncthreads();
        // ---- z mini-reduce (wave 0; other waves proceed to accumulate) ----
        if (t < 64) {
            int h = t & 7, seg = t >> 3;
            float z = 0.f;
            for (int nn = seg; nn < TILE; nn += 8) z += cbuf[nn][h];
            z += __shfl_xor(z, 8);
            z += __shfl_xor(z, 16);
            z += __shfl_xor(z, 32);
            if (t < 8) zrun += z;
        }
        // ---- accumulate wemb from LDS tile (p broadcast from cbuf) ----
        for (int nn = jr; nn < TILE; nn += 8) {
            float4 e = tile4[nn][c4 ^ (nn & 31)];
            float4 pA = *(const float4*)&cbuf[nn][0];
            float4 pB = *(const float4*)&cbuf[nn][4];
            wacc[0].x += pA.x * e.x; wacc[0].y += pA.x * e.y; wacc[0].z += pA.x * e.z; wacc[0].w += pA.x * e.w;
            wacc[1].x += pA.y * e.x; wacc[1].y += pA.y * e.y; wacc[1].z += pA.y * e.z; wacc[1].w += pA.y * e.w;
            wacc[2].x += pA.z * e.x; wacc[2].y += pA.z * e.y; wacc[2].z += pA.z * e.z; wacc[2].w += pA.z * e.w;
            wacc[3].x += pA.w * e.x; wacc[3].y += pA.w * e.y; wacc[3].z += pA.w * e.z; wacc[3].w += pA.w * e.w;
            wacc[4].x += pB.x * e.x; wacc[4].y += pB.x * e.y; wacc[4].z += pB.x * e.z; wacc[4].w += pB.x * e.w;
            wacc[5].x += pB.y * e.x; wacc[5].y += pB.y * e.y; wacc[5].z += pB.y * e.z; wacc[5].w += pB.y * e.w;
            wacc[6].x += pB.z * e.x; wacc[6].y += pB.z * e.y; wacc[6].z += pB.z * e.z; wacc[6].w += pB.z * e.w;
            wacc[7].x += pB.w * e.x; wacc[7].y += pB.w * e.y; wacc[7].z += pB.w * e.z; wacc[7].w += pB.w * e.w;
        }
        __syncthreads();   // tile4/cbuf dead before next stage
    }
    if (t < 8) zl[t] = zrun;
    // ---- j-reduce wemb partials (tile4 as [8][32][8] f4 scratch), normalize ----
    {
        float4* red = (float4*)&tile4[0][0];
#pragma unroll
        for (int h = 0; h < HH; ++h) red[(jr * 32 + c4) * 8 + h] = wacc[h];
        __syncthreads();
        int cc = t >> 3, hh = t & 7;
        float4 s = make_float4(0.f, 0.f, 0.f, 0.f);
#pragma unroll
        for (int jj = 0; jj < 8; ++jj) {
            float4 v = red[(jj * 32 + cc) * 8 + hh];
            s.x += v.x; s.y += v.y; s.z += v.z; s.w += v.w;
        }
        float inv = 1.0f / zl[hh];
        s.x *= inv; s.y *= inv; s.z *= inv; s.w *= inv;
        *(float4*)&wemb_s[hh][cc * 4] = s;
    }
    __syncthreads();
    // ---- glimpse tail ----
    if (t < 128) {
        int h = t >> 4;
        float a = 0.f;
        for (int c = 0; c < DD; ++c) a += wemb_s[h][c] * W_node[(size_t)c * 384 + 128 + t];
        small[t] = a;                          // hl
    }
    __syncthreads();
    if (t < 128) {
        float g = 0.f;
        for (int k = 0; k < DD; ++k) g += small[k] * W_out[k * DD + t];
        small[128 + t] = g;                    // gl
    }
    __syncthreads();
    if (t < 128) {
        float a3 = 0.f;
        const float* wr = W_node + (size_t)t * 384 + 256;   // Wl row t
        for (int d = 0; d < DD; ++d) a3 += wr[d] * small[128 + d];
        small[256 + t] = a3;                   // g2
    }
    __syncthreads();
    // ---- logits tail ----
    const float4* g2v = (const float4*)&small[256];
    for (int r = t; r < NN; r += 256) {
        const float4* row = embB4 + (size_t)r * 32;
        float acc = 0.f;
#pragma unroll 8
        for (int k = 0; k < 32; ++k) {
            float4 e = row[k], g = g2v[k];
            acc += e.x * g.x + e.y * g.y + e.z * g.z + e.w * g.w;
        }
        bool feas = mask_feasible(mask, flag, mbase + r);
        out[(size_t)mbase + r] = feas ? (10.0f * tanhf(acc * 0.08838834764831845f)) : -1.0e30f;
    }
}

extern "C" void kernel_launch(void* const* d_in, const int* in_sizes, int n_in,
                              void* d_out, int out_size, void* d_ws, size_t ws_size,
                              hipStream_t stream) {
    (void)in_sizes; (void)n_in; (void)out_size; (void)ws_size;
    const float* emb     = (const float*)d_in[0];
    const float* ctx     = (const float*)d_in[1];
    const float* W_node  = (const float*)d_in[2];
    const float* W_fixed = (const float*)d_in[3];
    const float* W_step  = (const float*)d_in[4];
    const float* W_out   = (const float*)d_in[5];
    const void*  mask    = d_in[6];
    float* out = (float*)d_out;

    char* ws = (char*)d_ws;
    int*   flag  = (int*)(ws + 0);
    float* Afold = (float*)(ws + WS_AFOLD);

    k0_detect<<<1, 64, 0, stream>>>((const unsigned int*)mask, flag);
    kA_meanfold<<<BB, 512, 0, stream>>>(emb, ctx, W_fixed, W_step, W_node, Afold);
    kB_flash<<<BB, 256, 0, stream>>>(emb, Afold, mask, flag, W_node, W_out, out);
}

// Round 19
// 166.442 us; speedup vs baseline: 1.6675x; 1.1109x over previous
//
#include <hip/hip_runtime.h>
#include <math.h>

#define BB 512
#define NN 1000
#define DD 128
#define HH 8
#define TILE 125   // 8 tiles of 125 rows; 4000 float4/tile

// ws layout: flag@0 (4B) | Afold@4096: [B][128][8] f32 (2 MB)
#define WS_AFOLD 4096

__device__ __forceinline__ bool mask_feasible(const void* mask, int flag, int idx) {
    if (flag == 1) return ((const int*)mask)[idx] != 0;
    if (flag == 2) return ((const float*)mask)[idx] != 0.0f;
    return ((const unsigned char*)mask)[idx] != 0;
}

// async 16B global->LDS DMA: per-lane global src addr; LDS dest is
// wave-uniform base + lane*16 (HW). No VGPR round-trip, can't spill.
__device__ __forceinline__ void gload_lds16(const float4* g, float4* l) {
    __builtin_amdgcn_global_load_lds(
        (const __attribute__((address_space(1))) void*)g,
        (__attribute__((address_space(3))) void*)l,
        16, 0, 0);
}

// Detect action_mask storage dtype from its first 64 32-bit words.
__global__ void k0_detect(const unsigned int* __restrict__ m, int* __restrict__ flag) {
    int t = threadIdx.x;
    unsigned int w = m[t];
    unsigned long long bi = __ballot(w <= 1u);
    unsigned long long bf = __ballot(w == 0u || w == 0x3F800000u);
    if (t == 0) {
        int f = 0;
        if (bi == ~0ull) f = 1;
        else if (bf == ~0ull) f = 2;
        *flag = f;
    }
}

// Fused: mean over N -> q = mean@W_fixed + ctx@W_step -> Afold[c][h]
// (validated R4/R12; single-arg launch_bounds only — R5: 2nd arg caused spill.)
__global__ __launch_bounds__(512) void kA_meanfold(
    const float* __restrict__ emb, const float* __restrict__ ctx,
    const float* __restrict__ W_fixed, const float* __restrict__ W_step,
    const float* __restrict__ W_node, float* __restrict__ Afold) {
    int b = blockIdx.x, t = threadIdx.x;
    __shared__ float4 red[512];
    __shared__ float mean_s[DD], cld[2 * DD], qlds[DD];
    int q4 = t & 31, j = t >> 5;
    const float4* e4 = (const float4*)(emb + (size_t)b * NN * DD);
    float4 acc = {0.f, 0.f, 0.f, 0.f};
    for (int n = j; n < NN; n += 16) {
        float4 v = e4[n * 32 + q4];
        acc.x += v.x; acc.y += v.y; acc.z += v.z; acc.w += v.w;
    }
    red[t] = acc;
    __syncthreads();
    for (int s = 8; s >= 1; s >>= 1) {
        if (j < s) {
            float4 o = red[t + s * 32], m = red[t];
            m.x += o.x; m.y += o.y; m.z += o.z; m.w += o.w;
            red[t] = m;
        }
        __syncthreads();
    }
    if (t < 32) {
        float4 m = red[t];
        const float inv = 1.0f / (float)NN;
        ((float4*)mean_s)[t] = make_float4(m.x * inv, m.y * inv, m.z * inv, m.w * inv);
    }
    if (t < 256) cld[t] = ctx[b * 2 * DD + t];
    __syncthreads();
    if (t < 128) {
        float a = 0.f;
        for (int c = 0; c < DD; ++c)     a += mean_s[c] * W_fixed[c * DD + t];
        for (int c = 0; c < 2 * DD; ++c) a += cld[c] * W_step[c * DD + t];
        qlds[t] = a;
    }
    __syncthreads();
    if (t < 128) {
        const float* wrow = W_node + (size_t)t * 3 * DD;   // Wk cols [0,128)
        float* A2 = Afold + (size_t)b * 1024;
        for (int h = 0; h < HH; ++h) {
            float a = 0.f;
#pragma unroll
            for (int d0 = 0; d0 < 16; ++d0) a += wrow[h * 16 + d0] * qlds[h * 16 + d0];
            A2[t * 8 + h] = 0.25f * a;   // 1/sqrt(dk) folded
        }
    }
}

// R18's kB with ONE delta: compat's A-operands come from wave-uniform SGPR
// loads (readfirstlane-scalarized base -> s_load, A-operand in the FMA's
// scalar slot) instead of lane-distributed VGPRs + v_readlane. Deletes 512
// readlane VALU ops per thread per tile; staging/accumulate/z untouched.
__global__ __launch_bounds__(256) void kB_flash(
    const float* __restrict__ emb, const float* __restrict__ Afold,
    const void* __restrict__ mask, const int* __restrict__ flagp,
    const float* __restrict__ W_node, const float* __restrict__ W_out,
    float* __restrict__ out) {
    int b = blockIdx.x, t = threadIdx.x;
    int flag = *flagp;
    int wave = t >> 6, lane = t & 63;
    int hq = (t >> 7) * 4;               // waves 0,1 -> h0..3 ; 2,3 -> h4..7
    int n = t & 127;                     // compat row (valid < TILE)
    int c4 = t & 31, jr = t >> 5;        // accumulate role (jr 0..7)

    __shared__ float4 tile4[128][32];    // 64 KB staged tile (XOR-swizzled); reused as j-reduce scratch
    __shared__ float cbuf[128][8];       // 4 KB: p values
    __shared__ float wemb_s[8][128];
    __shared__ float small[3 * DD];      // hl / gl / g2
    __shared__ float zl[HH];

    // wave-uniform scalar base into A: Afold[b][.][hq..hq+3]
    int hqs = __builtin_amdgcn_readfirstlane(hq);
    const float* AbW = Afold + (size_t)b * 1024 + hqs;

    float4 wacc[8];
#pragma unroll
    for (int h = 0; h < HH; ++h) wacc[h] = make_float4(0.f, 0.f, 0.f, 0.f);
    float zrun = 0.f;                    // meaningful on t<8 only

    const float4* embB4 = (const float4*)(emb + (size_t)b * NN * DD);
    const int mbase = b * NN;
    float4* tl = (float4*)tile4;

    for (int tile = 0; tile < 8; ++tile) {
        int n0 = tile * TILE;
        // ---- stage tile -> LDS via async DMA (wave-uniform LDS base,
        //      per-lane pre-swizzled global source; layout == R12) ----
        for (int i = wave; i < 63; i += 4) {
            int p0 = i * 64;                     // wave-uniform linear base
            int p = p0 + lane;
            int r = p >> 5; if (r > 124) r = 124;   // clamp tail overread
            int c = (p & 31) ^ (r & 31);
            gload_lds16(embB4 + (size_t)(n0 + r) * 32 + c, &tl[p0]);
        }
        __syncthreads();                         // drains vmcnt before reads
        // ---- compat from LDS -> p = exp(compat); A from SGPRs ----
        if (n < TILE) {
            int sw = n & 31;
            float4 s = make_float4(0.f, 0.f, 0.f, 0.f);
#pragma unroll 8
            for (int k = 0; k < 32; ++k) {          // col quad c = 4k..4k+3
                float4 e = tile4[n][k ^ sw];
                const float* ak = AbW + k * 32;     // A[4k+j][hq+i] = ak[j*8+i]
                s.x += e.x * ak[0] + e.y * ak[8]  + e.z * ak[16] + e.w * ak[24];
                s.y += e.x * ak[1] + e.y * ak[9]  + e.z * ak[17] + e.w * ak[25];
                s.z += e.x * ak[2] + e.y * ak[10] + e.z * ak[18] + e.w * ak[26];
                s.w += e.x * ak[3] + e.y * ak[11] + e.z * ak[19] + e.w * ak[27];
            }
            bool feas = mask_feasible(mask, flag, mbase + n0 + n);
            float4 p = make_float4(0.f, 0.f, 0.f, 0.f);
            if (feas) {
                p.x = __expf(s.x); p.y = __expf(s.y);
                p.z = __expf(s.z); p.w = __expf(s.w);
            }
            *(float4*)&cbuf[n][hq] = p;
        }
        __syncthreads();
        // ---- z mini-reduce (wave 0; other waves proceed to accumulate) ----
        if (t < 64) {
            int h = t & 7, seg = t >> 3;
            float z = 0.f;
            for (int nn = seg; nn < TILE; nn += 8) z += cbuf[nn][h];
            z += __shfl_xor(z, 8);
            z += __shfl_xor(z, 16);
            z += __shfl_xor(z, 32);
            if (t < 8) zrun += z;
        }
        // ---- accumulate wemb from LDS tile (p broadcast from cbuf) ----
        for (int nn = jr; nn < TILE; nn += 8) {
            float4 e = tile4[nn][c4 ^ (nn & 31)];
            float4 pA = *(const float4*)&cbuf[nn][0];
            float4 pB = *(const float4*)&cbuf[nn][4];
            wacc[0].x += pA.x * e.x; wacc[0].y += pA.x * e.y; wacc[0].z += pA.x * e.z; wacc[0].w += pA.x * e.w;
            wacc[1].x += pA.y * e.x; wacc[1].y += pA.y * e.y; wacc[1].z += pA.y * e.z; wacc[1].w += pA.y * e.w;
            wacc[2].x += pA.z * e.x; wacc[2].y += pA.z * e.y; wacc[2].z += pA.z * e.z; wacc[2].w += pA.z * e.w;
            wacc[3].x += pA.w * e.x; wacc[3].y += pA.w * e.y; wacc[3].z += pA.w * e.z; wacc[3].w += pA.w * e.w;
            wacc[4].x += pB.x * e.x; wacc[4].y += pB.x * e.y; wacc[4].z += pB.x * e.z; wacc[4].w += pB.x * e.w;
            wacc[5].x += pB.y * e.x; wacc[5].y += pB.y * e.y; wacc[5].z += pB.y * e.z; wacc[5].w += pB.y * e.w;
            wacc[6].x += pB.z * e.x; wacc[6].y += pB.z * e.y; wacc[6].z += pB.z * e.z; wacc[6].w += pB.z * e.w;
            wacc[7].x += pB.w * e.x; wacc[7].y += pB.w * e.y; wacc[7].z += pB.w * e.z; wacc[7].w += pB.w * e.w;
        }
        __syncthreads();   // tile4/cbuf dead before next stage
    }
    if (t < 8) zl[t] = zrun;
    // ---- j-reduce wemb partials (tile4 as [8][32][8] f4 scratch), normalize ----
    {
        float4* red = (float4*)&tile4[0][0];
#pragma unroll
        for (int h = 0; h < HH; ++h) red[(jr * 32 + c4) * 8 + h] = wacc[h];
        __syncthreads();
        int cc = t >> 3, hh = t & 7;
        float4 s = make_float4(0.f, 0.f, 0.f, 0.f);
#pragma unroll
        for (int jj = 0; jj < 8; ++jj) {
            float4 v = red[(jj * 32 + cc) * 8 + hh];
            s.x += v.x; s.y += v.y; s.z += v.z; s.w += v.w;
        }
        float inv = 1.0f / zl[hh];
        s.x *= inv; s.y *= inv; s.z *= inv; s.w *= inv;
        *(float4*)&wemb_s[hh][cc * 4] = s;
    }
    __syncthreads();
    // ---- glimpse tail ----
    if (t < 128) {
        int h = t >> 4;
        float a = 0.f;
        for (int c = 0; c < DD; ++c) a += wemb_s[h][c] * W_node[(size_t)c * 384 + 128 + t];
        small[t] = a;                          // hl
    }
    __syncthreads();
    if (t < 128) {
        float g = 0.f;
        for (int k = 0; k < DD; ++k) g += small[k] * W_out[k * DD + t];
        small[128 + t] = g;                    // gl
    }
    __syncthreads();
    if (t < 128) {
        float a3 = 0.f;
        const float* wr = W_node + (size_t)t * 384 + 256;   // Wl row t
        for (int d = 0; d < DD; ++d) a3 += wr[d] * small[128 + d];
        small[256 + t] = a3;                   // g2
    }
    __syncthreads();
    // ---- logits tail ----
    const float4* g2v = (const float4*)&small[256];
    for (int r = t; r < NN; r += 256) {
        const float4* row = embB4 + (size_t)r * 32;
        float acc = 0.f;
#pragma unroll 8
        for (int k = 0; k < 32; ++k) {
            float4 e = row[k], g = g2v[k];
            acc += e.x * g.x + e.y * g.y + e.z * g.z + e.w * g.w;
        }
        bool feas = mask_feasible(mask, flag, mbase + r);
        out[(size_t)mbase + r] = feas ? (10.0f * tanhf(acc * 0.08838834764831845f)) : -1.0e30f;
    }
}

extern "C" void kernel_launch(void* const* d_in, const int* in_sizes, int n_in,
                              void* d_out, int out_size, void* d_ws, size_t ws_size,
                              hipStream_t stream) {
    (void)in_sizes; (void)n_in; (void)out_size; (void)ws_size;
    const float* emb     = (const float*)d_in[0];
    const float* ctx     = (const float*)d_in[1];
    const float* W_node  = (const float*)d_in[2];
    const float* W_fixed = (const float*)d_in[3];
    const float* W_step  = (const float*)d_in[4];
    const float* W_out   = (const float*)d_in[5];
    const void*  mask    = d_in[6];
    float* out = (float*)d_out;

    char* ws = (char*)d_ws;
    int*   flag  = (int*)(ws + 0);
    float* Afold = (float*)(ws + WS_AFOLD);

    k0_detect<<<1, 64, 0, stream>>>((const unsigned int*)mask, flag);
    kA_meanfold<<<BB, 512, 0, stream>>>(emb, ctx, W_fixed, W_step, W_node, Afold);
    kB_flash<<<BB, 256, 0, stream>>>(emb, Afold, mask, flag, W_node, W_out, out);
}